// Round 6
// baseline (392.808 us; speedup 1.0000x reference)
//
#include <hip/hip_runtime.h>

// CPQuadRankLayer: B=64, N=1024, C=4, R=64, D=128, fp32.
//   projected[b,n,c,r] = sum_i x[b,n,c,i] * factors[c,n,r,i]
//   p = projected * rsqrt(mean_r(projected^2) + 1e-6)
//   merged[b,n,r] = p0*p1*p2*p3 * gain[n]
//   out[b,n,o] = sum_r merged[b,n,r]*factor_out[n,r,o] + 0.25*sum_c x[b,n,c,o]
//
// R9 = R8 with the occupancy pin removed via explicit waves_per_eu(2,8).
//  Ledger: achieved waves/EU == launch_bounds 2nd arg in all clean runs
//  (2->21.5%, 3->27%, 4->43%) regardless of resources -> the single-value
//  "amdgpu-waves-per-eu=N" emitted by __launch_bounds__ acts as an
//  effective MAX. The allocator also keys its VGPR budget off it
//  (>=3 -> spill-to-target; 2 -> clean VGPR=100). Splitting the two:
//  amdgpu_waves_per_eu(2,8) keeps the allocator in the known no-spill
//  min=2 regime while letting runtime residency go resource-limited:
//  VGPR=100 + LDS 32 KiB -> 4 blocks/CU = grid's 1024/256 -> all
//  co-resident.
//  Kept from R8 (verified spill-free, -15us): barrier-free phase 1 with
//  per-wave counted s_waitcnt vmcnt(4) (wave-private staging; never-drain),
//  one __syncthreads before phase 3; 32 KiB LDS with pT folded into Sbuf;
//  factor_out direct from global (unroll 8); fully-unrolled acc[][]
//  (R2/R4/R7 scratch lesson).

constexpr int Nn = 1024;
constexpr int Cc = 4;
constexpr int Dd = 128;
constexpr int Rr = 64;
constexpr int IC = 8;             // i-chunk depth
constexpr int NCH = Dd / IC;      // 16 chunks

typedef __attribute__((address_space(3))) float lds_float;
typedef __attribute__((address_space(1))) const float gbl_float;

// async global->LDS: per-lane global src, wave-uniform LDS base (+lane*16 by HW)
__device__ __forceinline__ void ald16(const float* g, const float* l) {
  __builtin_amdgcn_global_load_lds((gbl_float*)g,
                                   (lds_float*)(uint32_t)(uintptr_t)l,
                                   16, 0, 0);
}

__device__ __forceinline__ int row_of_slot(int s) {
  const int a = s >> 3;
  return 8 * a + ((s & 7) ^ a);   // inverse of slot(8a+j)=8a+(j^a)
}

__global__
__attribute__((amdgpu_flat_work_group_size(256, 256), amdgpu_waves_per_eu(2, 8)))
void cpquad_kernel(const float* __restrict__ x,
                   const float* __restrict__ factors,
                   const float* __restrict__ factor_out,
                   const float* __restrict__ gain,
                   float* __restrict__ out) {
  // 32 KiB total. Phase 1: f region [0,4096) floats, x region [4096,8192),
  // each split as (p*4+c)*512 + slot*8 + i (slot-swizzled, DMA-linear).
  // Phase 3/4: rows 0..63 x stride 72 = 4608 floats of Sbuf reused as pT.
  __shared__ alignas(16) float Sbuf[8192];

  const int n   = blockIdx.x;
  const int tid = threadIdx.x;
  const int c   = tid >> 6;       // wave = child
  const int l   = tid & 63;
  const int bg  = l & 7;          // b-group
  const int rg  = l >> 3;         // r-group (also o-group in phase 4)
  const int h   = l & 1;

  // ---- DMA source addresses (slot-swizzled rows) ----
  const int s0 = l >> 1, s1 = 32 + (l >> 1);
  const int r0 = row_of_slot(s0), r1 = row_of_slot(s1);
  const float* fcn = factors + (((size_t)c * Nn + n) * Rr) * Dd;
  const float* fsrc0 = fcn + r0 * Dd + h * 4;
  const float* fsrc1 = fcn + r1 * Dd + h * 4;
  const float* xsrc0 = x + (((size_t)r0 * Nn + n) * Cc + c) * Dd + h * 4;
  const float* xsrc1 = x + (((size_t)r1 * Nn + n) * Cc + c) * Dd + h * 4;

  // ---- prologue: stage chunk 0 into buffer 0 (4 DMAs in flight) ----
  {
    float* fw = Sbuf + c * 512;
    float* xw = Sbuf + 4096 + c * 512;
    ald16(fsrc0, fw);  ald16(fsrc1, fw + 256);
    ald16(xsrc0, xw);  ald16(xsrc1, xw + 256);
  }

  float acc[8][8];
#pragma unroll
  for (int kk = 0; kk < 8; ++kk)
#pragma unroll
    for (int jj = 0; jj < 8; ++jj) acc[kk][jj] = 0.0f;

  // LDS read offsets (floats) for this lane's 8 f-rows / 8 x-rows
  int fof[8], xof[8];
#pragma unroll
  for (int t = 0; t < 8; ++t) {
    fof[t] = (8 * rg + (t ^ rg)) * 8;
    xof[t] = (8 * bg + (t ^ bg)) * 8;
  }

  // ---------------- Phase 1: projection GEMM (barrier-free) ----------------
  // Wave-private staging + per-wave counted vmcnt. No __syncthreads in the
  // loop; prefetch of chunk ch+1 stays in flight across chunk ch's compute.
#pragma unroll 1
  for (int ch = 0; ch < NCH; ++ch) {
    const int p = ch & 1;
    if (ch + 1 < NCH) {
      const int i0 = (ch + 1) * IC;
      float* fw = Sbuf + ((p ^ 1) * 4 + c) * 512;
      float* xw = Sbuf + 4096 + ((p ^ 1) * 4 + c) * 512;
      ald16(fsrc0 + i0, fw);  ald16(fsrc1 + i0, fw + 256);
      ald16(xsrc0 + i0, xw);  ald16(xsrc1 + i0, xw + 256);
      // 8 outstanding (4 of chunk ch, 4 of ch+1). FIFO vmcnt(4): chunk ch's
      // 4 have landed; ch+1's 4 keep flying across the FMAs below.
      asm volatile("s_waitcnt vmcnt(4)" ::: "memory");
    } else {
      asm volatile("s_waitcnt vmcnt(0)" ::: "memory");
    }
    const float* fr = Sbuf + (p * 4 + c) * 512;
    const float* xr = Sbuf + 4096 + (p * 4 + c) * 512;
#pragma unroll
    for (int hh = 0; hh < 2; ++hh) {
      float4 fv[8], xv[8];
#pragma unroll
      for (int jj = 0; jj < 8; ++jj)
        fv[jj] = *(const float4*)(fr + fof[jj] + hh * 4);
#pragma unroll
      for (int kk = 0; kk < 8; ++kk)
        xv[kk] = *(const float4*)(xr + xof[kk] + hh * 4);
#pragma unroll
      for (int kk = 0; kk < 8; ++kk)
#pragma unroll
        for (int jj = 0; jj < 8; ++jj) {
          float a = acc[kk][jj];
          a = fmaf(xv[kk].x, fv[jj].x, a);
          a = fmaf(xv[kk].y, fv[jj].y, a);
          a = fmaf(xv[kk].z, fv[jj].z, a);
          a = fmaf(xv[kk].w, fv[jj].w, a);
          acc[kk][jj] = a;
        }
    }
    // no barrier: buffer p^1 is next overwritten only after all FMAs that
    // consumed it (program order), and the DMA write-back is ~900cy out.
  }

  // ---------------- Phase 2: RMSNorm over r (register-only) ----------------
  float scale[8];
  {
    const float g = gain[n];
#pragma unroll
    for (int kk = 0; kk < 8; ++kk) {
      float s = 0.0f;
#pragma unroll
      for (int jj = 0; jj < 8; ++jj) s = fmaf(acc[kk][jj], acc[kk][jj], s);
      s += __shfl_xor(s, 8);      // reduce across rg (lane bits 3..5)
      s += __shfl_xor(s, 16);
      s += __shfl_xor(s, 32);
      float sc = 1.0f / sqrtf(s * (1.0f / 64.0f) + 1e-6f);
      if (c == 0) sc *= g;        // fold gain once into child 0
      scale[kk] = sc;
    }
  }

  // ---------------- Phase 3: quartic product into pT[r][b] --------------
  // pT reuses Sbuf (phase-1 staging dead). stride 72 -> 2-way banks, 16B ok.
  float (*pT)[72] = reinterpret_cast<float(*)[72]>(Sbuf);

  __syncthreads();  // first cross-wave dependency: all waves done with Sbuf

#pragma unroll
  for (int w = 0; w < 4; ++w) {
    if (c == w) {
#pragma unroll
      for (int jj = 0; jj < 8; ++jj) {
        float4 lo, hi;
        lo.x = acc[0][jj] * scale[0];  lo.y = acc[1][jj] * scale[1];
        lo.z = acc[2][jj] * scale[2];  lo.w = acc[3][jj] * scale[3];
        hi.x = acc[4][jj] * scale[4];  hi.y = acc[5][jj] * scale[5];
        hi.z = acc[6][jj] * scale[6];  hi.w = acc[7][jj] * scale[7];
        float4* dst = (float4*)&pT[8 * rg + jj][8 * bg];
        if (w == 0) {
          dst[0] = lo;  dst[1] = hi;
        } else {
          float4 a0 = dst[0], a1 = dst[1];
          a0.x *= lo.x; a0.y *= lo.y; a0.z *= lo.z; a0.w *= lo.w;
          a1.x *= hi.x; a1.y *= hi.y; a1.z *= hi.z; a1.w *= hi.w;
          dst[0] = a0;  dst[1] = a1;
        }
      }
    }
    __syncthreads();  // order the 4 multiplicative passes
  }

  // ---------------- Phase 4: output projection ----------------
  // wave c owns o in [32c, 32c+32); lane tile 8b x 4o.
  // factor_out read straight from global (n-private, read once, 128B/row
  // per wave coalesced; 8-lane same-address groups broadcast). unroll 8
  // keeps 8 independent fo loads in flight to cover the cold-HBM latency.
  const int o0 = c * 32 + rg * 4;
  const float* fog = factor_out + (size_t)n * Rr * Dd + o0;
  float4 a2[8];
#pragma unroll
  for (int kk = 0; kk < 8; ++kk) a2[kk] = make_float4(0.f, 0.f, 0.f, 0.f);

#pragma unroll 8
  for (int r = 0; r < Rr; ++r) {
    const float4 m0 = *(const float4*)&pT[r][8 * bg];
    const float4 m1 = *(const float4*)&pT[r][8 * bg + 4];
    const float4 f  = *(const float4*)(fog + (size_t)r * Dd);
    a2[0].x = fmaf(m0.x, f.x, a2[0].x); a2[0].y = fmaf(m0.x, f.y, a2[0].y);
    a2[0].z = fmaf(m0.x, f.z, a2[0].z); a2[0].w = fmaf(m0.x, f.w, a2[0].w);
    a2[1].x = fmaf(m0.y, f.x, a2[1].x); a2[1].y = fmaf(m0.y, f.y, a2[1].y);
    a2[1].z = fmaf(m0.y, f.z, a2[1].z); a2[1].w = fmaf(m0.y, f.w, a2[1].w);
    a2[2].x = fmaf(m0.z, f.x, a2[2].x); a2[2].y = fmaf(m0.z, f.y, a2[2].y);
    a2[2].z = fmaf(m0.z, f.z, a2[2].z); a2[2].w = fmaf(m0.z, f.w, a2[2].w);
    a2[3].x = fmaf(m0.w, f.x, a2[3].x); a2[3].y = fmaf(m0.w, f.y, a2[3].y);
    a2[3].z = fmaf(m0.w, f.z, a2[3].z); a2[3].w = fmaf(m0.w, f.w, a2[3].w);
    a2[4].x = fmaf(m1.x, f.x, a2[4].x); a2[4].y = fmaf(m1.x, f.y, a2[4].y);
    a2[4].z = fmaf(m1.x, f.z, a2[4].z); a2[4].w = fmaf(m1.x, f.w, a2[4].w);
    a2[5].x = fmaf(m1.y, f.x, a2[5].x); a2[5].y = fmaf(m1.y, f.y, a2[5].y);
    a2[5].z = fmaf(m1.y, f.z, a2[5].z); a2[5].w = fmaf(m1.y, f.w, a2[5].w);
    a2[6].x = fmaf(m1.z, f.x, a2[6].x); a2[6].y = fmaf(m1.z, f.y, a2[6].y);
    a2[6].z = fmaf(m1.z, f.z, a2[6].z); a2[6].w = fmaf(m1.z, f.w, a2[6].w);
    a2[7].x = fmaf(m1.w, f.x, a2[7].x); a2[7].y = fmaf(m1.w, f.y, a2[7].y);
    a2[7].z = fmaf(m1.w, f.z, a2[7].z); a2[7].w = fmaf(m1.w, f.w, a2[7].w);
  }

  // ---------------- epilogue: residual + store ----------------
#pragma unroll
  for (int kk = 0; kk < 8; ++kk) {
    const int b = 8 * bg + kk;
    const float* xb = x + (((size_t)b * Nn + n) * Cc) * Dd + o0;
    float4 t0 = *(const float4*)(xb);
    float4 t1 = *(const float4*)(xb + Dd);
    float4 t2 = *(const float4*)(xb + 2 * Dd);
    float4 t3 = *(const float4*)(xb + 3 * Dd);
    float4 v;
    v.x = a2[kk].x + 0.25f * (t0.x + t1.x + t2.x + t3.x);
    v.y = a2[kk].y + 0.25f * (t0.y + t1.y + t2.y + t3.y);
    v.z = a2[kk].z + 0.25f * (t0.z + t1.z + t2.z + t3.z);
    v.w = a2[kk].w + 0.25f * (t0.w + t1.w + t2.w + t3.w);
    *(float4*)(out + ((size_t)b * Nn + n) * Dd + o0) = v;
  }
}

extern "C" void kernel_launch(void* const* d_in, const int* in_sizes, int n_in,
                              void* d_out, int out_size, void* d_ws, size_t ws_size,
                              hipStream_t stream) {
  const float* x          = (const float*)d_in[0];
  const float* factors    = (const float*)d_in[1];
  const float* factor_out = (const float*)d_in[2];
  const float* gain       = (const float*)d_in[3];
  float* out              = (float*)d_out;
  hipLaunchKernelGGL(cpquad_kernel, dim3(Nn), dim3(256), 0, stream,
                     x, factors, factor_out, gain, out);
}

// Round 7
// 383.649 us; speedup vs baseline: 1.0239x; 1.0239x over previous
//
#include <hip/hip_runtime.h>

// CPQuadRankLayer: B=64, N=1024, C=4, R=64, D=128, fp32.
//   projected[b,n,c,r] = sum_i x[b,n,c,i] * factors[c,n,r,i]
//   p = projected * rsqrt(mean_r(projected^2) + 1e-6)
//   merged[b,n,r] = p0*p1*p2*p3 * gain[n]
//   out[b,n,o] = sum_r merged[b,n,r]*factor_out[n,r,o] + 0.25*sum_c x[b,n,c,o]
//
// R10 = R3's fo-DMA-staging + R8's barrier-free phase 1 (combine the two
// measured wins; they were never tested together).
//  Ledger: R3 (barriers, fo-staged, 50KiB) = 187us; R6 (barriers,
//  fo-global, 32KiB) = 209us -> fo staging worth ~-20us. R8 (barrier-free,
//  fo-global, 32KiB) = 194us -> barrier-free worth ~-15us vs R6.
//  Occupancy is pinned at ~21.5% regardless of LDS (32K/50K), waves_per_eu
//  metadata (R9 null), or launch_bounds; raising it via allocator coercion
//  spills (R4/R5/R7). So the 50 KiB layout costs nothing -> reinstate
//  pT[64][72] separate and stage fo into Sbuf via DMA.
//  Structure: barrier-free phase 1 (wave-private staging, counted
//  s_waitcnt vmcnt(4) never-drain) -> __syncthreads (required: fo sections
//  overlap other waves' staging) -> issue fo DMA (32 KiB, flies under
//  phases 2-3; drained by each wave's own vmcnt(0) before the phase-3
//  barriers) -> RMSNorm (registers) -> quartic into pT -> phase 4 from LDS.
//  launch_bounds(256,2): only proven spill-free setting (VGPR=100,
//  WRITE_SIZE=33MB). acc[][] fully unrolled (R2/R4/R7 scratch lesson).

constexpr int Nn = 1024;
constexpr int Cc = 4;
constexpr int Dd = 128;
constexpr int Rr = 64;
constexpr int IC = 8;             // i-chunk depth
constexpr int NCH = Dd / IC;      // 16 chunks

typedef __attribute__((address_space(3))) float lds_float;
typedef __attribute__((address_space(1))) const float gbl_float;

// async global->LDS: per-lane global src, wave-uniform LDS base (+lane*16 by HW)
__device__ __forceinline__ void ald16(const float* g, const float* l) {
  __builtin_amdgcn_global_load_lds((gbl_float*)g,
                                   (lds_float*)(uint32_t)(uintptr_t)l,
                                   16, 0, 0);
}

__device__ __forceinline__ int row_of_slot(int s) {
  const int a = s >> 3;
  return 8 * a + ((s & 7) ^ a);   // inverse of slot(8a+j)=8a+(j^a)
}

__global__ __launch_bounds__(256, 2)
void cpquad_kernel(const float* __restrict__ x,
                   const float* __restrict__ factors,
                   const float* __restrict__ factor_out,
                   const float* __restrict__ gain,
                   float* __restrict__ out) {
  // Sbuf 32 KiB: phase 1 staging (f [0,4096) floats, x [4096,8192), each
  // (p*4+c)*512 + slot*8 + i, slot-swizzled, DMA-linear). Reused flat as
  // factor_out[n] ([64r][128o]) in phase 4.
  // pT[r][b]: separate transposed merged buffer; stride 72 -> 2-way banks.
  __shared__ alignas(16) float Sbuf[8192];
  __shared__ alignas(16) float pT[Rr][72];

  const int n   = blockIdx.x;
  const int tid = threadIdx.x;
  const int c   = tid >> 6;       // wave = child
  const int l   = tid & 63;
  const int bg  = l & 7;          // b-group
  const int rg  = l >> 3;         // r-group (also o-group in phase 4)
  const int h   = l & 1;

  // ---- DMA source addresses (slot-swizzled rows) ----
  const int s0 = l >> 1, s1 = 32 + (l >> 1);
  const int r0 = row_of_slot(s0), r1 = row_of_slot(s1);
  const float* fcn = factors + (((size_t)c * Nn + n) * Rr) * Dd;
  const float* fsrc0 = fcn + r0 * Dd + h * 4;
  const float* fsrc1 = fcn + r1 * Dd + h * 4;
  const float* xsrc0 = x + (((size_t)r0 * Nn + n) * Cc + c) * Dd + h * 4;
  const float* xsrc1 = x + (((size_t)r1 * Nn + n) * Cc + c) * Dd + h * 4;

  // ---- prologue: stage chunk 0 into buffer 0 (4 DMAs in flight) ----
  {
    float* fw = Sbuf + c * 512;
    float* xw = Sbuf + 4096 + c * 512;
    ald16(fsrc0, fw);  ald16(fsrc1, fw + 256);
    ald16(xsrc0, xw);  ald16(xsrc1, xw + 256);
  }

  float acc[8][8];
#pragma unroll
  for (int kk = 0; kk < 8; ++kk)
#pragma unroll
    for (int jj = 0; jj < 8; ++jj) acc[kk][jj] = 0.0f;

  // LDS read offsets (floats) for this lane's 8 f-rows / 8 x-rows
  int fof[8], xof[8];
#pragma unroll
  for (int t = 0; t < 8; ++t) {
    fof[t] = (8 * rg + (t ^ rg)) * 8;
    xof[t] = (8 * bg + (t ^ bg)) * 8;
  }

  // ---------------- Phase 1: projection GEMM (barrier-free) ----------------
  // Wave-private staging + per-wave counted vmcnt. No __syncthreads in the
  // loop; prefetch of chunk ch+1 stays in flight across chunk ch's compute.
#pragma unroll 1
  for (int ch = 0; ch < NCH; ++ch) {
    const int p = ch & 1;
    if (ch + 1 < NCH) {
      const int i0 = (ch + 1) * IC;
      float* fw = Sbuf + ((p ^ 1) * 4 + c) * 512;
      float* xw = Sbuf + 4096 + ((p ^ 1) * 4 + c) * 512;
      ald16(fsrc0 + i0, fw);  ald16(fsrc1 + i0, fw + 256);
      ald16(xsrc0 + i0, xw);  ald16(xsrc1 + i0, xw + 256);
      // 8 outstanding (4 of chunk ch, 4 of ch+1). FIFO vmcnt(4): chunk ch's
      // 4 have landed; ch+1's 4 keep flying across the FMAs below.
      asm volatile("s_waitcnt vmcnt(4)" ::: "memory");
    } else {
      asm volatile("s_waitcnt vmcnt(0)" ::: "memory");
    }
    const float* fr = Sbuf + (p * 4 + c) * 512;
    const float* xr = Sbuf + 4096 + (p * 4 + c) * 512;
#pragma unroll
    for (int hh = 0; hh < 2; ++hh) {
      float4 fv[8], xv[8];
#pragma unroll
      for (int jj = 0; jj < 8; ++jj)
        fv[jj] = *(const float4*)(fr + fof[jj] + hh * 4);
#pragma unroll
      for (int kk = 0; kk < 8; ++kk)
        xv[kk] = *(const float4*)(xr + xof[kk] + hh * 4);
#pragma unroll
      for (int kk = 0; kk < 8; ++kk)
#pragma unroll
        for (int jj = 0; jj < 8; ++jj) {
          float a = acc[kk][jj];
          a = fmaf(xv[kk].x, fv[jj].x, a);
          a = fmaf(xv[kk].y, fv[jj].y, a);
          a = fmaf(xv[kk].z, fv[jj].z, a);
          a = fmaf(xv[kk].w, fv[jj].w, a);
          acc[kk][jj] = a;
        }
    }
    // no barrier: buffer p^1 is next overwritten only after all FMAs that
    // consumed it (program order), and the DMA write-back is ~900cy out.
  }

  // All waves must finish reading Sbuf before fo staging overwrites it
  // (wave c's fo sections overlap other waves' staging regions).
  __syncthreads();

  // ---- stage factor_out[n] (32 KiB flat) into Sbuf; flies under ph 2-3 ----
  {
    const float* fob = factor_out + (size_t)n * Rr * Dd;
#pragma unroll
    for (int k = 0; k < 8; ++k) {
      const int sec = k * 4 + c;                    // wave-uniform
      ald16(fob + sec * 256 + l * 4, Sbuf + sec * 256);
    }
  }

  // ---------------- Phase 2: RMSNorm over r (register-only) ----------------
  float scale[8];
  {
    const float g = gain[n];
#pragma unroll
    for (int kk = 0; kk < 8; ++kk) {
      float s = 0.0f;
#pragma unroll
      for (int jj = 0; jj < 8; ++jj) s = fmaf(acc[kk][jj], acc[kk][jj], s);
      s += __shfl_xor(s, 8);      // reduce across rg (lane bits 3..5)
      s += __shfl_xor(s, 16);
      s += __shfl_xor(s, 32);
      float sc = 1.0f / sqrtf(s * (1.0f / 64.0f) + 1e-6f);
      if (c == 0) sc *= g;        // fold gain once into child 0
      scale[kk] = sc;
    }
  }

  // ---------------- Phase 3: quartic product into pT[r][b] --------------
#pragma unroll
  for (int w = 0; w < 4; ++w) {
    if (c == w) {
#pragma unroll
      for (int jj = 0; jj < 8; ++jj) {
        float4 lo, hi;
        lo.x = acc[0][jj] * scale[0];  lo.y = acc[1][jj] * scale[1];
        lo.z = acc[2][jj] * scale[2];  lo.w = acc[3][jj] * scale[3];
        hi.x = acc[4][jj] * scale[4];  hi.y = acc[5][jj] * scale[5];
        hi.z = acc[6][jj] * scale[6];  hi.w = acc[7][jj] * scale[7];
        float4* dst = (float4*)&pT[8 * rg + jj][8 * bg];
        if (w == 0) {
          dst[0] = lo;  dst[1] = hi;
        } else {
          float4 a0 = dst[0], a1 = dst[1];
          a0.x *= lo.x; a0.y *= lo.y; a0.z *= lo.z; a0.w *= lo.w;
          a1.x *= hi.x; a1.y *= hi.y; a1.z *= hi.z; a1.w *= hi.w;
          dst[0] = a0;  dst[1] = a1;
        }
      }
    }
    __syncthreads();  // order passes; each wave's own vmcnt(0) before its
                      // barrier arrival also drains its fo DMA by the last.
  }

  // ---------------- Phase 4: output projection ----------------
  // wave c owns o in [32c, 32c+32); lane tile 8b x 4o; fo from LDS
  // (r*128 + o0: rg*4 spreads banks, 8-lane bg groups broadcast).
  const int o0 = c * 32 + rg * 4;
  float4 a2[8];
#pragma unroll
  for (int kk = 0; kk < 8; ++kk) a2[kk] = make_float4(0.f, 0.f, 0.f, 0.f);

#pragma unroll 8
  for (int r = 0; r < Rr; ++r) {
    const float4 m0 = *(const float4*)&pT[r][8 * bg];
    const float4 m1 = *(const float4*)&pT[r][8 * bg + 4];
    const float4 f  = *(const float4*)(Sbuf + r * Dd + o0);
    a2[0].x = fmaf(m0.x, f.x, a2[0].x); a2[0].y = fmaf(m0.x, f.y, a2[0].y);
    a2[0].z = fmaf(m0.x, f.z, a2[0].z); a2[0].w = fmaf(m0.x, f.w, a2[0].w);
    a2[1].x = fmaf(m0.y, f.x, a2[1].x); a2[1].y = fmaf(m0.y, f.y, a2[1].y);
    a2[1].z = fmaf(m0.y, f.z, a2[1].z); a2[1].w = fmaf(m0.y, f.w, a2[1].w);
    a2[2].x = fmaf(m0.z, f.x, a2[2].x); a2[2].y = fmaf(m0.z, f.y, a2[2].y);
    a2[2].z = fmaf(m0.z, f.z, a2[2].z); a2[2].w = fmaf(m0.z, f.w, a2[2].w);
    a2[3].x = fmaf(m0.w, f.x, a2[3].x); a2[3].y = fmaf(m0.w, f.y, a2[3].y);
    a2[3].z = fmaf(m0.w, f.z, a2[3].z); a2[3].w = fmaf(m0.w, f.w, a2[3].w);
    a2[4].x = fmaf(m1.x, f.x, a2[4].x); a2[4].y = fmaf(m1.x, f.y, a2[4].y);
    a2[4].z = fmaf(m1.x, f.z, a2[4].z); a2[4].w = fmaf(m1.x, f.w, a2[4].w);
    a2[5].x = fmaf(m1.y, f.x, a2[5].x); a2[5].y = fmaf(m1.y, f.y, a2[5].y);
    a2[5].z = fmaf(m1.y, f.z, a2[5].z); a2[5].w = fmaf(m1.y, f.w, a2[5].w);
    a2[6].x = fmaf(m1.z, f.x, a2[6].x); a2[6].y = fmaf(m1.z, f.y, a2[6].y);
    a2[6].z = fmaf(m1.z, f.z, a2[6].z); a2[6].w = fmaf(m1.z, f.w, a2[6].w);
    a2[7].x = fmaf(m1.w, f.x, a2[7].x); a2[7].y = fmaf(m1.w, f.y, a2[7].y);
    a2[7].z = fmaf(m1.w, f.z, a2[7].z); a2[7].w = fmaf(m1.w, f.w, a2[7].w);
  }

  // ---------------- epilogue: residual + store ----------------
#pragma unroll
  for (int kk = 0; kk < 8; ++kk) {
    const int b = 8 * bg + kk;
    const float* xb = x + (((size_t)b * Nn + n) * Cc) * Dd + o0;
    float4 t0 = *(const float4*)(xb);
    float4 t1 = *(const float4*)(xb + Dd);
    float4 t2 = *(const float4*)(xb + 2 * Dd);
    float4 t3 = *(const float4*)(xb + 3 * Dd);
    float4 v;
    v.x = a2[kk].x + 0.25f * (t0.x + t1.x + t2.x + t3.x);
    v.y = a2[kk].y + 0.25f * (t0.y + t1.y + t2.y + t3.y);
    v.z = a2[kk].z + 0.25f * (t0.z + t1.z + t2.z + t3.z);
    v.w = a2[kk].w + 0.25f * (t0.w + t1.w + t2.w + t3.w);
    *(float4*)(out + ((size_t)b * Nn + n) * Dd + o0) = v;
  }
}

extern "C" void kernel_launch(void* const* d_in, const int* in_sizes, int n_in,
                              void* d_out, int out_size, void* d_ws, size_t ws_size,
                              hipStream_t stream) {
  const float* x          = (const float*)d_in[0];
  const float* factors    = (const float*)d_in[1];
  const float* factor_out = (const float*)d_in[2];
  const float* gain       = (const float*)d_in[3];
  float* out              = (float*)d_out;
  hipLaunchKernelGGL(cpquad_kernel, dim3(Nn), dim3(256), 0, stream,
                     x, factors, factor_out, gain, out);
}